// Round 3
// baseline (446.650 us; speedup 1.0000x reference)
//
#include <hip/hip_runtime.h>

// MoonVitEncoderLayer on MI355X (gfx950).
// S=4096, D=1152, H=16, HD=72 (padded to 96), MLPD=4304 (padded to 4352).
// cu_seqlens is always arange(9)*512 -> block-diagonal attention, 8 segs of 512.
// R2: GEMM tiles widened: 256x128/BK=64 (8 waves) for qkv/fc0, 128x128/BK=64
//     (4 waves) for wo/fc1. Same verified 2-phase double-buffer sync structure.

#define DEV __device__ __forceinline__

typedef __attribute__((ext_vector_type(8))) short short8;
typedef __attribute__((ext_vector_type(4))) float f32x4;

typedef const void __attribute__((address_space(1))) gvoid;
typedef void __attribute__((address_space(3))) lvoid;

DEV ushort f2bf(float f) {
  union { float f; unsigned u; } x; x.f = f;
  unsigned r = (x.u + 0x7FFFu + ((x.u >> 16) & 1u)) >> 16;
  return (ushort)r;
}

DEV float bf2f(ushort u) {
  union { unsigned u; float f; } x; x.u = (unsigned)u << 16;
  return x.f;
}

DEV void gload_lds16(const void* g, void* l) {
  __builtin_amdgcn_global_load_lds((gvoid*)g, (lvoid*)l, 16, 0, 0);
}

DEV f32x4 mfma16(short8 a, short8 b, f32x4 c) {
  return __builtin_amdgcn_mfma_f32_16x16x32_bf16(a, b, c, 0, 0, 0);
}

DEV float gelu_tanh(float x) {
  float x3 = x * x * x;
  return 0.5f * x * (1.f + tanhf(0.7978845608f * (x + 0.044715f * x3)));
}

// ---------------- weight convert + transpose: src f32 (K,N) -> dst bf16 (NP,KP), zero-padded
__global__ void wconv_t(const float* __restrict__ src, ushort* __restrict__ dst,
                        int K, int N, int NP, int KP) {
  __shared__ float tile[32][33];
  const int k0 = blockIdx.x * 32, n0 = blockIdx.y * 32;
  const int tx = threadIdx.x & 31, ty = threadIdx.x >> 5; // ty 0..7
#pragma unroll
  for (int i = 0; i < 4; ++i) {
    int r = ty + i * 8;
    float v = 0.f;
    if (k0 + r < K && n0 + tx < N) v = src[(size_t)(k0 + r) * N + n0 + tx];
    tile[tx][r] = v;
  }
  __syncthreads();
#pragma unroll
  for (int i = 0; i < 4; ++i) {
    int r = ty + i * 8;
    dst[(size_t)(n0 + r) * KP + k0 + tx] = f2bf(tile[r][tx]);
  }
}

// ---------------- LayerNorm row kernel: f32 (4096,1152) -> bf16
__global__ __launch_bounds__(256) void ln_bf16(const float* __restrict__ x,
                                               const float* __restrict__ sc,
                                               const float* __restrict__ bi,
                                               ushort* __restrict__ out) {
  const int row = blockIdx.x, tid = threadIdx.x;
  const float* xr = x + (size_t)row * 1152;
  const int n = (tid < 128) ? 5 : 4;
  float vals[5];
  float s = 0.f, s2 = 0.f;
#pragma unroll
  for (int i = 0; i < 5; ++i) {
    if (i < n) { float v = xr[tid + i * 256]; vals[i] = v; s += v; s2 += v * v; }
  }
#pragma unroll
  for (int off = 32; off; off >>= 1) { s += __shfl_xor(s, off); s2 += __shfl_xor(s2, off); }
  __shared__ float rs[4], rs2[4];
  if ((tid & 63) == 0) { rs[tid >> 6] = s; rs2[tid >> 6] = s2; }
  __syncthreads();
  s = rs[0] + rs[1] + rs[2] + rs[3];
  s2 = rs2[0] + rs2[1] + rs2[2] + rs2[3];
  const float mean = s * (1.f / 1152.f);
  const float var = s2 * (1.f / 1152.f) - mean * mean;
  const float rstd = rsqrtf(var + 1e-5f);
  ushort* orow = out + (size_t)row * 1152;
  for (int i = 0; i < n; ++i) {
    int c = tid + i * 256;
    orow[c] = f2bf((vals[i] - mean) * rstd * sc[c] + bi[c]);
  }
}

// ---------------- GEMM: A (M,K) bf16 rm, Bt (N,K) bf16 rm, C = A*B
// 2-phase double-buffered pipeline. Tile BM x 128, BK=64.
// BM=256: 512 thr (8 waves, 4Mx2N); BM=128: 256 thr (4 waves, 2Mx2N).
// Per-wave output 64x64 (acc[4][4]) in both variants.
// EPI 1: outf = resid + C + bias    (wo -> h, fc1 -> out)
// EPI 2: outh = bf16(gelu(C+bias))  (fc0 -> mid)
// EPI 3: outh = bf16(C + bias)      (qkv)
template <int EPI, int BM>
__global__ __launch_bounds__(BM == 256 ? 512 : 256, 2) void gemm_bt(
    const ushort* __restrict__ A, const ushort* __restrict__ Bt,
    const float* __restrict__ bias, const float* __restrict__ resid,
    float* __restrict__ outf, ushort* __restrict__ outh,
    int N, int K, int n_valid) {
  constexpr int T = (BM == 256) ? 512 : 256;       // threads
  constexpr int LOADS_A = BM * 8 / T;              // 4
  constexpr int LOADS_B = 128 * 8 / T;             // 2 or 4
  __shared__ ushort lA[2][BM * 64];
  __shared__ ushort lB[2][128 * 64];
  const int tid = threadIdx.x;
  const int lane = tid & 63, wave = tid >> 6;
  const int l15 = lane & 15, lg = lane >> 4;

  // XCD-aware bijective swizzle (all grids have nwg % 8 == 0)
  const int nx = gridDim.x;
  const int nwg = nx * gridDim.y;
  int flat = blockIdx.y * nx + blockIdx.x;
  flat = (flat & 7) * (nwg >> 3) + (flat >> 3);
  const int bx = flat % nx, by = flat / nx;
  const int m0 = by * BM, n0 = bx * 128;

  const int wm = (wave >> 1) * 64;
  const int wn = (wave & 1) * 64;

  f32x4 acc[4][4] = {};

  // staging: chunk c covers lA row c>>3, k-offset (c&7)*8
  size_t arow[LOADS_A], brow[LOADS_B];
#pragma unroll
  for (int i = 0; i < LOADS_A; ++i) {
    int c = i * T + tid;
    arow[i] = (size_t)(m0 + (c >> 3)) * K + (c & 7) * 8;
  }
#pragma unroll
  for (int i = 0; i < LOADS_B; ++i) {
    int c = i * T + tid;
    brow[i] = (size_t)(n0 + (c >> 3)) * K + (c & 7) * 8;
  }

  auto stage = [&](int b, int kt) {
#pragma unroll
    for (int i = 0; i < LOADS_A; ++i)
      gload_lds16(A + arow[i] + kt, &lA[b][(i * T + wave * 64) * 8]);
#pragma unroll
    for (int i = 0; i < LOADS_B; ++i)
      gload_lds16(Bt + brow[i] + kt, &lB[b][(i * T + wave * 64) * 8]);
  };

  stage(0, 0);
  __syncthreads();
  int cur = 0;
  for (int kt = 0; kt < K; kt += 64) {
    if (kt + 64 < K) stage(cur ^ 1, kt + 64); // prefetch next tile, in flight during MFMA
#pragma unroll
    for (int ks = 0; ks < 2; ++ks) {
      short8 af[4], bfr[4];
#pragma unroll
      for (int i = 0; i < 4; ++i)
        af[i] = *(const short8*)&lA[cur][(wm + i * 16 + l15) * 64 + ks * 32 + lg * 8];
#pragma unroll
      for (int j = 0; j < 4; ++j)
        bfr[j] = *(const short8*)&lB[cur][(wn + j * 16 + l15) * 64 + ks * 32 + lg * 8];
#pragma unroll
      for (int i = 0; i < 4; ++i)
#pragma unroll
        for (int j = 0; j < 4; ++j)
          acc[i][j] = mfma16(af[i], bfr[j], acc[i][j]);
    }
    __syncthreads(); // drains vmcnt(0)+lgkmcnt(0): prefetch landed, lA/lB[cur] reusable
    cur ^= 1;
  }

  const int cb = n0 + wn + l15;
  const int rb = m0 + wm + lg * 4;
#pragma unroll
  for (int j = 0; j < 4; ++j) {
    const int col = cb + j * 16;
    const float bv = (col < n_valid) ? bias[col] : 0.f;
#pragma unroll
    for (int i = 0; i < 4; ++i) {
#pragma unroll
      for (int r = 0; r < 4; ++r) {
        const int row = rb + i * 16 + r;
        const size_t idx = (size_t)row * N + col;
        const float v = acc[i][j][r] + bv;
        if constexpr (EPI == 1) outf[idx] = resid[idx] + v;
        else if constexpr (EPI == 2) outh[idx] = f2bf(gelu_tanh(v));
        else outh[idx] = f2bf(v);
      }
    }
  }
}

// ---------------- RoPE + pack q,k: qkv bf16 (S,3456) -> q_pad,k_pad bf16 (H,S,96), q pre-scaled
__global__ void rope_pack(const ushort* __restrict__ qkv,
                          const float* __restrict__ cosp, const float* __restrict__ sinp,
                          ushort* __restrict__ qp, ushort* __restrict__ kp) {
  const int t = blockIdx.x * 256 + threadIdx.x; // S*H*96 total
  const int d = t % 96;
  const int hs = t / 96;
  const int h = hs & 15;
  const int s = hs >> 4;
  const size_t dst = ((size_t)h * 4096 + s) * 96 + d;
  if (d >= 72) { qp[dst] = 0; kp[dst] = 0; return; }
  const int i = d >> 1;
  const float c = cosp[s * 36 + i], sn = sinp[s * 36 + i];
  const size_t base = (size_t)s * 3456 + h * 72;
  const float q0 = bf2f(qkv[base + (d & ~1)]), q1 = bf2f(qkv[base + (d | 1)]);
  const float k0 = bf2f(qkv[base + 1152 + (d & ~1)]), k1 = bf2f(qkv[base + 1152 + (d | 1)]);
  float qo, ko;
  if ((d & 1) == 0) { qo = q0 * c - q1 * sn; ko = k0 * c - k1 * sn; }
  else              { qo = q0 * sn + q1 * c; ko = k0 * sn + k1 * c; }
  qp[dst] = f2bf(qo * 0.1178511302f); // 72^-0.5 folded into q
  kp[dst] = f2bf(ko);
}

// ---------------- V pack + transpose: qkv bf16 -> vt bf16 (H,96,S), d>=72 zero
__global__ void v_pack(const ushort* __restrict__ qkv, ushort* __restrict__ vt) {
  __shared__ ushort lv[96][64];
  const int b = blockIdx.x;
  const int h = b >> 6;
  const int s0 = (b & 63) << 6;
  const int tid = threadIdx.x;
#pragma unroll
  for (int it = 0; it < 24; ++it) {
    int idx = tid + it * 256; // 96*64
    int d = idx % 96, sl = idx / 96;
    lv[d][sl] = (d < 72) ? qkv[(size_t)(s0 + sl) * 3456 + 2304 + h * 72 + d] : (ushort)0;
  }
  __syncthreads();
#pragma unroll
  for (int it = 0; it < 24; ++it) {
    int idx = tid + it * 256;
    int d = idx >> 6, sl = idx & 63;
    vt[((size_t)h * 96 + d) * 4096 + s0 + sl] = lv[d][sl];
  }
}

// ---------------- block-diagonal flash attention
// grid: 16 heads * 8 segs * 8 qtiles = 1024 blocks; 4 waves, 16 q-rows each
__global__ __launch_bounds__(256) void attn_kernel(
    const ushort* __restrict__ qp, const ushort* __restrict__ kp,
    const ushort* __restrict__ vt, ushort* __restrict__ attn_out) {
  __shared__ ushort lp[4][16 * 32];
  const int tid = threadIdx.x, lane = tid & 63, wave = tid >> 6;
  const int l15 = lane & 15, lg = lane >> 4;
  const int b = blockIdx.x;
  const int h = b >> 6;
  const int rem = b & 63;
  const int seg = rem >> 3, qt = rem & 7;
  const int q0 = seg * 512 + qt * 64 + wave * 16;

  short8 aq[3];
  const ushort* qrow = qp + ((size_t)h * 4096 + q0 + l15) * 96 + lg * 8;
  aq[0] = *(const short8*)(qrow);
  aq[1] = *(const short8*)(qrow + 32);
  aq[2] = *(const short8*)(qrow + 64);

  f32x4 oacc[5] = {};
  float mrow[4] = {-1e30f, -1e30f, -1e30f, -1e30f};
  float srow[4] = {0.f, 0.f, 0.f, 0.f};

  const ushort* kbase = kp + ((size_t)h * 4096 + seg * 512) * 96;
  const ushort* vbase = vt + (size_t)h * 96 * 4096 + seg * 512;
  ushort* lpw = lp[wave];

  for (int kc = 0; kc < 16; ++kc) {
    f32x4 sc[2] = {};
#pragma unroll
    for (int n = 0; n < 2; ++n) {
      const ushort* krow = kbase + (size_t)(kc * 32 + n * 16 + l15) * 96 + lg * 8;
#pragma unroll
      for (int c = 0; c < 3; ++c) {
        short8 kb = *(const short8*)(krow + c * 32);
        sc[n] = mfma16(aq[c], kb, sc[n]);
      }
    }
    float corr[4];
#pragma unroll
    for (int j = 0; j < 4; ++j) {
      float v = fmaxf(sc[0][j], sc[1][j]);
      v = fmaxf(v, __shfl_xor(v, 1));
      v = fmaxf(v, __shfl_xor(v, 2));
      v = fmaxf(v, __shfl_xor(v, 4));
      v = fmaxf(v, __shfl_xor(v, 8));
      float mn = fmaxf(mrow[j], v);
      corr[j] = __expf(mrow[j] - mn);
      mrow[j] = mn;
    }
    float p0[4], p1[4];
#pragma unroll
    for (int j = 0; j < 4; ++j) {
      p0[j] = __expf(sc[0][j] - mrow[j]);
      p1[j] = __expf(sc[1][j] - mrow[j]);
      float ps = p0[j] + p1[j];
      ps += __shfl_xor(ps, 1);
      ps += __shfl_xor(ps, 2);
      ps += __shfl_xor(ps, 4);
      ps += __shfl_xor(ps, 8);
      srow[j] = srow[j] * corr[j] + ps;
    }
#pragma unroll
    for (int n = 0; n < 5; ++n)
#pragma unroll
      for (int j = 0; j < 4; ++j)
        oacc[n][j] *= corr[j];
    // P (16x32) -> LDS transpose staging
#pragma unroll
    for (int j = 0; j < 4; ++j) {
      int row = lg * 4 + j;
      lpw[row * 32 + l15] = f2bf(p0[j]);
      lpw[row * 32 + 16 + l15] = f2bf(p1[j]);
    }
    __syncthreads();
    short8 pa = *(const short8*)&lpw[l15 * 32 + lg * 8];
    const ushort* vrow = vbase + kc * 32 + lg * 8;
#pragma unroll
    for (int n = 0; n < 5; ++n) {
      short8 vb = *(const short8*)(vrow + (size_t)(n * 16 + l15) * 4096);
      oacc[n] = mfma16(pa, vb, oacc[n]);
    }
    __syncthreads();
  }
#pragma unroll
  for (int j = 0; j < 4; ++j) {
    float inv = 1.f / srow[j];
    int row = q0 + lg * 4 + j;
#pragma unroll
    for (int n = 0; n < 5; ++n) {
      int col = n * 16 + l15;
      if (col < 72)
        attn_out[(size_t)row * 1152 + h * 72 + col] = f2bf(oacc[n][j] * inv);
    }
  }
}

// ---------------- launch
extern "C" void kernel_launch(void* const* d_in, const int* in_sizes, int n_in,
                              void* d_out, int out_size, void* d_ws, size_t ws_size,
                              hipStream_t stream) {
  (void)in_sizes; (void)n_in; (void)out_size;
  const float* hidden = (const float*)d_in[0];
  // d_in[1] = cu_seqlens: always arange(9)*512 (uniform 512 segments), handled structurally
  const float* ropec = (const float*)d_in[2];
  const float* ropes = (const float*)d_in[3];
  const float* n0s = (const float*)d_in[4];
  const float* n0b = (const float*)d_in[5];
  const float* wqkv = (const float*)d_in[6];
  const float* bqkv = (const float*)d_in[7];
  const float* wo = (const float*)d_in[8];
  const float* bo = (const float*)d_in[9];
  const float* n1s = (const float*)d_in[10];
  const float* n1b = (const float*)d_in[11];
  const float* wfc0 = (const float*)d_in[12];
  const float* bfc0 = (const float*)d_in[13];
  const float* wfc1 = (const float*)d_in[14];
  const float* bfc1 = (const float*)d_in[15];
  float* out = (float*)d_out;

  char* ws = (char*)d_ws;
  // workspace layout (bytes)
  ushort* x_bf   = (ushort*)(ws + 0);            //  9,437,184  (4096x1152 bf16)
  ushort* wqkv_t = (ushort*)(ws + 9437184);      //  7,962,624  (3456x1152 bf16)
  ushort* wo_t   = (ushort*)(ws + 17399808);     //  2,654,208  (1152x1152)
  ushort* fc0_t  = (ushort*)(ws + 20054016);     // 10,027,008  (4352x1152)
  ushort* fc1_t  = (ushort*)(ws + 30081024);     // 10,027,008  (1152x4352)
  ushort* qkv_bf = (ushort*)(ws + 40108032);     // 28,311,552  (4096x3456 bf16)
  ushort* mid    = (ushort*)(ws + 40108032);     // 35,651,584  (4096x4352 bf16) aliases qkv_bf (dead by then)
  ushort* q_pad  = (ushort*)(ws + 96731136);     // 12,582,912  (16x4096x96)
  ushort* k_pad  = (ushort*)(ws + 109314048);    // 12,582,912
  ushort* vt     = (ushort*)(ws + 121896960);    // 12,582,912  (16x96x4096)
  ushort* attn   = (ushort*)(ws + 134479872);    //  9,437,184  (4096x1152 bf16)
  float*  hbuf   = (float*)(ws + 143917056);     // 18,874,368  (4096x1152 f32)
  ushort* yln    = (ushort*)(ws + 162791424);    //  9,437,184
  if (ws_size < 172228608) return;

  // 1. weight transposes (f32 KxN -> bf16 NPxKP)
  wconv_t<<<dim3(36, 108), 256, 0, stream>>>(wqkv, wqkv_t, 1152, 3456, 3456, 1152);
  wconv_t<<<dim3(36, 36), 256, 0, stream>>>(wo, wo_t, 1152, 1152, 1152, 1152);
  wconv_t<<<dim3(36, 136), 256, 0, stream>>>(wfc0, fc0_t, 1152, 4304, 4352, 1152);
  wconv_t<<<dim3(136, 36), 256, 0, stream>>>(wfc1, fc1_t, 4304, 1152, 1152, 4352);

  // 2. LN0
  ln_bf16<<<4096, 256, 0, stream>>>(hidden, n0s, n0b, x_bf);

  // 3. QKV GEMM -> bf16 (256x128 tile, 512 thr; grid 27x16 = 432)
  gemm_bt<3, 256><<<dim3(27, 16), 512, 0, stream>>>(x_bf, wqkv_t, bqkv, nullptr, nullptr, qkv_bf,
                                                    3456, 1152, 3456);
  // 4. RoPE pack q,k ; 5. V transpose
  rope_pack<<<24576, 256, 0, stream>>>(qkv_bf, ropec, ropes, q_pad, k_pad);
  v_pack<<<1024, 256, 0, stream>>>(qkv_bf, vt);

  // 6. attention
  attn_kernel<<<1024, 256, 0, stream>>>(q_pad, k_pad, vt, attn);

  // 7. WO GEMM + residual -> h (128x128 tile; grid 9x32 = 288)
  gemm_bt<1, 128><<<dim3(9, 32), 256, 0, stream>>>(attn, wo_t, bo, hidden, hbuf, nullptr,
                                                   1152, 1152, 1152);
  // 8. LN1
  ln_bf16<<<4096, 256, 0, stream>>>(hbuf, n1s, n1b, yln);

  // 9. FC0 GEMM + gelu -> mid (256x128 tile; grid 34x16 = 544)
  gemm_bt<2, 256><<<dim3(34, 16), 512, 0, stream>>>(yln, fc0_t, bfc0, nullptr, nullptr, mid,
                                                    4352, 1152, 4304);
  // 10. FC1 GEMM + h residual -> out (128x128 tile; grid 9x32 = 288)
  gemm_bt<1, 128><<<dim3(9, 32), 256, 0, stream>>>(mid, fc1_t, bfc1, hbuf, out, nullptr,
                                                   1152, 4352, 1152);
}

// Round 4
// 381.814 us; speedup vs baseline: 1.1698x; 1.1698x over previous
//
#include <hip/hip_runtime.h>

// MoonVitEncoderLayer on MI355X (gfx950).
// S=4096, D=1152, H=16, HD=72 (padded to 96), MLPD=4304 (padded to 4352).
// cu_seqlens is always arange(9)*512 -> block-diagonal attention, 8 segs of 512.
// R3: unified deep-pipelined GEMM (T2+T3+T4+T5): BM=256 x BN=128 x BK=64,
//     8 waves, XOR-swizzled LDS (both-sides), raw s_barrier + counted vmcnt(6)
//     (never 0 in loop), setprio around MFMA clusters.

#define DEV __device__ __forceinline__

typedef __attribute__((ext_vector_type(8))) short short8;
typedef __attribute__((ext_vector_type(4))) float f32x4;

typedef const void __attribute__((address_space(1))) gvoid;
typedef void __attribute__((address_space(3))) lvoid;

DEV ushort f2bf(float f) {
  union { float f; unsigned u; } x; x.f = f;
  unsigned r = (x.u + 0x7FFFu + ((x.u >> 16) & 1u)) >> 16;
  return (ushort)r;
}

DEV float bf2f(ushort u) {
  union { unsigned u; float f; } x; x.u = (unsigned)u << 16;
  return x.f;
}

DEV void gload_lds16(const void* g, void* l) {
  __builtin_amdgcn_global_load_lds((gvoid*)g, (lvoid*)l, 16, 0, 0);
}

DEV f32x4 mfma16(short8 a, short8 b, f32x4 c) {
  return __builtin_amdgcn_mfma_f32_16x16x32_bf16(a, b, c, 0, 0, 0);
}

DEV float gelu_tanh(float x) {
  float x3 = x * x * x;
  return 0.5f * x * (1.f + tanhf(0.7978845608f * (x + 0.044715f * x3)));
}

// ---------------- weight convert + transpose: src f32 (K,N) -> dst bf16 (NP,KP), zero-padded
__global__ void wconv_t(const float* __restrict__ src, ushort* __restrict__ dst,
                        int K, int N, int NP, int KP) {
  __shared__ float tile[32][33];
  const int k0 = blockIdx.x * 32, n0 = blockIdx.y * 32;
  const int tx = threadIdx.x & 31, ty = threadIdx.x >> 5; // ty 0..7
#pragma unroll
  for (int i = 0; i < 4; ++i) {
    int r = ty + i * 8;
    float v = 0.f;
    if (k0 + r < K && n0 + tx < N) v = src[(size_t)(k0 + r) * N + n0 + tx];
    tile[tx][r] = v;
  }
  __syncthreads();
#pragma unroll
  for (int i = 0; i < 4; ++i) {
    int r = ty + i * 8;
    dst[(size_t)(n0 + r) * KP + k0 + tx] = f2bf(tile[r][tx]);
  }
}

// ---------------- LayerNorm row kernel: f32 (4096,1152) -> bf16
__global__ __launch_bounds__(256) void ln_bf16(const float* __restrict__ x,
                                               const float* __restrict__ sc,
                                               const float* __restrict__ bi,
                                               ushort* __restrict__ out) {
  const int row = blockIdx.x, tid = threadIdx.x;
  const float* xr = x + (size_t)row * 1152;
  const int n = (tid < 128) ? 5 : 4;
  float vals[5];
  float s = 0.f, s2 = 0.f;
#pragma unroll
  for (int i = 0; i < 5; ++i) {
    if (i < n) { float v = xr[tid + i * 256]; vals[i] = v; s += v; s2 += v * v; }
  }
#pragma unroll
  for (int off = 32; off; off >>= 1) { s += __shfl_xor(s, off); s2 += __shfl_xor(s2, off); }
  __shared__ float rs[4], rs2[4];
  if ((tid & 63) == 0) { rs[tid >> 6] = s; rs2[tid >> 6] = s2; }
  __syncthreads();
  s = rs[0] + rs[1] + rs[2] + rs[3];
  s2 = rs2[0] + rs2[1] + rs2[2] + rs2[3];
  const float mean = s * (1.f / 1152.f);
  const float var = s2 * (1.f / 1152.f) - mean * mean;
  const float rstd = rsqrtf(var + 1e-5f);
  ushort* orow = out + (size_t)row * 1152;
  for (int i = 0; i < n; ++i) {
    int c = tid + i * 256;
    orow[c] = f2bf((vals[i] - mean) * rstd * sc[c] + bi[c]);
  }
}

// ---------------- GEMM: A (M,K) bf16 rm, Bt (N,K) bf16 rm, C = A*B
// Deep-pipelined: BM=256, BN=128, BK=64, 512 thr (8 waves, 4M x 2N),
// per-wave 64x64 (acc[4][4]), 2-buffer LDS, raw barriers + counted vmcnt.
// LDS XOR-swizzle: physical chunk (r, c) holds logical (r, c ^ (r&7));
// staged via pre-swizzled GLOBAL source (linear gload_lds dest), read with
// chunk = (ks*4+lg) ^ (row&7)  -> 2-way conflicts only (free).
// EPI 1: outf = resid + C + bias    (wo -> h, fc1 -> out)
// EPI 2: outh = bf16(gelu(C+bias))  (fc0 -> mid)
// EPI 3: outh = bf16(C + bias)      (qkv)
template <int EPI>
__global__ __launch_bounds__(512, 2) void gemm8p(
    const ushort* __restrict__ A, const ushort* __restrict__ Bt,
    const float* __restrict__ bias, const float* __restrict__ resid,
    float* __restrict__ outf, ushort* __restrict__ outh,
    int N, int K, int n_valid) {
  __shared__ ushort lA[2][256 * 64]; // 2 x 32KB
  __shared__ ushort lB[2][128 * 64]; // 2 x 16KB
  const int tid = threadIdx.x;
  const int lane = tid & 63, wave = tid >> 6;
  const int l15 = lane & 15, lg = lane >> 4;
  const int wr = wave >> 1, wc = wave & 1;

  // XCD-aware bijective swizzle (all grids are multiples of 8)
  const int nx = gridDim.x;
  const int nwg = nx * gridDim.y;
  int flat = blockIdx.y * nx + blockIdx.x;
  flat = (flat & 7) * (nwg >> 3) + (flat >> 3);
  const int bx = flat % nx, by = flat / nx;
  const int m0 = by * 256, n0 = bx * 128;

  // ---- staging: thread covers row (i*64 + wave*8 + lane>>3), 16B chunk (lane&7)
  // global k-chunk pre-swizzled: kc = (lane&7) ^ (lane>>3)  [since row&7 == lane>>3]
  const int swz = ((lane & 7) ^ (lane >> 3)) * 8;
  const int rstg = wave * 8 + (lane >> 3);
  const ushort* Ag = A + (size_t)(m0 + rstg) * K + swz;
  const ushort* Bg = Bt + (size_t)(n0 + rstg) * K + swz;

  auto stage = [&](int b, int kt) { // 6 gload_lds per thread
#pragma unroll
    for (int i = 0; i < 4; ++i)
      gload_lds16(Ag + ((size_t)i * 64) * K + kt, &lA[b][i * 4096 + wave * 512]);
#pragma unroll
    for (int i = 0; i < 2; ++i)
      gload_lds16(Bg + ((size_t)i * 64) * K + kt, &lB[b][i * 4096 + wave * 512]);
  };

  f32x4 acc[4][4] = {};
  const int NT = K >> 6;

  stage(0, 0);
  stage(1, 64);
  asm volatile("s_waitcnt vmcnt(6)" ::: "memory"); // tile 0 landed (tile 1 in flight)
  __builtin_amdgcn_s_barrier();

  const int rowA = wr * 64 + l15; // + mf*16
  const int rowB = wc * 64 + l15; // + nf*16
  const int rx = l15 & 7;         // row&7 (mf*16/nf*16 don't change low 3 bits)
  int cA[2];
  cA[0] = (lg ^ rx) * 8;
  cA[1] = ((4 + lg) ^ rx) * 8;

  for (int t = 0; t < NT; ++t) {
    const int cur = t & 1;
    const ushort* la = lA[cur];
    const ushort* lb = lB[cur];
    short8 a0[2][2], a1[2][2], bfr[4][2];
    // phase 1 reads: A mf0-1 (4) + B all (8)
#pragma unroll
    for (int mf = 0; mf < 2; ++mf)
#pragma unroll
      for (int ks = 0; ks < 2; ++ks)
        a0[mf][ks] = *(const short8*)&la[(rowA + mf * 16) * 64 + cA[ks]];
#pragma unroll
    for (int nf = 0; nf < 4; ++nf)
#pragma unroll
      for (int ks = 0; ks < 2; ++ks)
        bfr[nf][ks] = *(const short8*)&lb[(rowB + nf * 16) * 64 + cA[ks]];
    __builtin_amdgcn_s_setprio(1);
#pragma unroll
    for (int mf = 0; mf < 2; ++mf)
#pragma unroll
      for (int nf = 0; nf < 4; ++nf)
#pragma unroll
        for (int ks = 0; ks < 2; ++ks)
          acc[mf][nf] = mfma16(a0[mf][ks], bfr[nf][ks], acc[mf][nf]);
    __builtin_amdgcn_s_setprio(0);
    // phase 2 reads: A mf2-3 (4)
#pragma unroll
    for (int mf = 0; mf < 2; ++mf)
#pragma unroll
      for (int ks = 0; ks < 2; ++ks)
        a1[mf][ks] = *(const short8*)&la[(rowA + (mf + 2) * 16) * 64 + cA[ks]];
    asm volatile("s_waitcnt lgkmcnt(0)" ::: "memory"); // this wave's buf[cur] reads retired
    __builtin_amdgcn_s_barrier();                      // all waves done with buf[cur]
    if (t + 2 < NT) stage(cur, (t + 2) << 6);          // overwrite buf[cur] with tile t+2
    __builtin_amdgcn_s_setprio(1);
#pragma unroll
    for (int mf = 0; mf < 2; ++mf)
#pragma unroll
      for (int nf = 0; nf < 4; ++nf)
#pragma unroll
        for (int ks = 0; ks < 2; ++ks)
          acc[mf + 2][nf] = mfma16(a1[mf][ks], bfr[nf][ks], acc[mf + 2][nf]);
    __builtin_amdgcn_s_setprio(0);
    if (t + 2 < NT) {
      asm volatile("s_waitcnt vmcnt(6)" ::: "memory"); // tile t+1 landed; t+2 in flight
      __builtin_amdgcn_sched_barrier(0);
      __builtin_amdgcn_s_barrier();
    } else if (t + 1 < NT) {
      asm volatile("s_waitcnt vmcnt(0)" ::: "memory"); // final tile landed
      __builtin_amdgcn_sched_barrier(0);
      __builtin_amdgcn_s_barrier();
    }
  }

  // epilogue
  const int cb = n0 + wc * 64 + l15;
  const int rb = m0 + wr * 64 + lg * 4;
#pragma unroll
  for (int j = 0; j < 4; ++j) {
    const int col = cb + j * 16;
    const float bv = (col < n_valid) ? bias[col] : 0.f;
#pragma unroll
    for (int i = 0; i < 4; ++i) {
#pragma unroll
      for (int r = 0; r < 4; ++r) {
        const int row = rb + i * 16 + r;
        const size_t idx = (size_t)row * N + col;
        const float v = acc[i][j][r] + bv;
        if constexpr (EPI == 1) outf[idx] = resid[idx] + v;
        else if constexpr (EPI == 2) outh[idx] = f2bf(gelu_tanh(v));
        else outh[idx] = f2bf(v);
      }
    }
  }
}

// ---------------- RoPE + pack q,k: qkv bf16 (S,3456) -> q_pad,k_pad bf16 (H,S,96), q pre-scaled
__global__ void rope_pack(const ushort* __restrict__ qkv,
                          const float* __restrict__ cosp, const float* __restrict__ sinp,
                          ushort* __restrict__ qp, ushort* __restrict__ kp) {
  const int t = blockIdx.x * 256 + threadIdx.x; // S*H*96 total
  const int d = t % 96;
  const int hs = t / 96;
  const int h = hs & 15;
  const int s = hs >> 4;
  const size_t dst = ((size_t)h * 4096 + s) * 96 + d;
  if (d >= 72) { qp[dst] = 0; kp[dst] = 0; return; }
  const int i = d >> 1;
  const float c = cosp[s * 36 + i], sn = sinp[s * 36 + i];
  const size_t base = (size_t)s * 3456 + h * 72;
  const float q0 = bf2f(qkv[base + (d & ~1)]), q1 = bf2f(qkv[base + (d | 1)]);
  const float k0 = bf2f(qkv[base + 1152 + (d & ~1)]), k1 = bf2f(qkv[base + 1152 + (d | 1)]);
  float qo, ko;
  if ((d & 1) == 0) { qo = q0 * c - q1 * sn; ko = k0 * c - k1 * sn; }
  else              { qo = q0 * sn + q1 * c; ko = k0 * sn + k1 * c; }
  qp[dst] = f2bf(qo * 0.1178511302f); // 72^-0.5 folded into q
  kp[dst] = f2bf(ko);
}

// ---------------- V pack + transpose: qkv bf16 -> vt bf16 (H,96,S), d>=72 zero
__global__ void v_pack(const ushort* __restrict__ qkv, ushort* __restrict__ vt) {
  __shared__ ushort lv[96][64];
  const int b = blockIdx.x;
  const int h = b >> 6;
  const int s0 = (b & 63) << 6;
  const int tid = threadIdx.x;
#pragma unroll
  for (int it = 0; it < 24; ++it) {
    int idx = tid + it * 256; // 96*64
    int d = idx % 96, sl = idx / 96;
    lv[d][sl] = (d < 72) ? qkv[(size_t)(s0 + sl) * 3456 + 2304 + h * 72 + d] : (ushort)0;
  }
  __syncthreads();
#pragma unroll
  for (int it = 0; it < 24; ++it) {
    int idx = tid + it * 256;
    int d = idx >> 6, sl = idx & 63;
    vt[((size_t)h * 96 + d) * 4096 + s0 + sl] = lv[d][sl];
  }
}

// ---------------- block-diagonal flash attention
// grid: 16 heads * 8 segs * 8 qtiles = 1024 blocks; 4 waves, 16 q-rows each
__global__ __launch_bounds__(256) void attn_kernel(
    const ushort* __restrict__ qp, const ushort* __restrict__ kp,
    const ushort* __restrict__ vt, ushort* __restrict__ attn_out) {
  __shared__ ushort lp[4][16 * 32];
  const int tid = threadIdx.x, lane = tid & 63, wave = tid >> 6;
  const int l15 = lane & 15, lg = lane >> 4;
  const int b = blockIdx.x;
  const int h = b >> 6;
  const int rem = b & 63;
  const int seg = rem >> 3, qt = rem & 7;
  const int q0 = seg * 512 + qt * 64 + wave * 16;

  short8 aq[3];
  const ushort* qrow = qp + ((size_t)h * 4096 + q0 + l15) * 96 + lg * 8;
  aq[0] = *(const short8*)(qrow);
  aq[1] = *(const short8*)(qrow + 32);
  aq[2] = *(const short8*)(qrow + 64);

  f32x4 oacc[5] = {};
  float mrow[4] = {-1e30f, -1e30f, -1e30f, -1e30f};
  float srow[4] = {0.f, 0.f, 0.f, 0.f};

  const ushort* kbase = kp + ((size_t)h * 4096 + seg * 512) * 96;
  const ushort* vbase = vt + (size_t)h * 96 * 4096 + seg * 512;
  ushort* lpw = lp[wave];

  for (int kc = 0; kc < 16; ++kc) {
    f32x4 sc[2] = {};
#pragma unroll
    for (int n = 0; n < 2; ++n) {
      const ushort* krow = kbase + (size_t)(kc * 32 + n * 16 + l15) * 96 + lg * 8;
#pragma unroll
      for (int c = 0; c < 3; ++c) {
        short8 kb = *(const short8*)(krow + c * 32);
        sc[n] = mfma16(aq[c], kb, sc[n]);
      }
    }
    float corr[4];
#pragma unroll
    for (int j = 0; j < 4; ++j) {
      float v = fmaxf(sc[0][j], sc[1][j]);
      v = fmaxf(v, __shfl_xor(v, 1));
      v = fmaxf(v, __shfl_xor(v, 2));
      v = fmaxf(v, __shfl_xor(v, 4));
      v = fmaxf(v, __shfl_xor(v, 8));
      float mn = fmaxf(mrow[j], v);
      corr[j] = __expf(mrow[j] - mn);
      mrow[j] = mn;
    }
    float p0[4], p1[4];
#pragma unroll
    for (int j = 0; j < 4; ++j) {
      p0[j] = __expf(sc[0][j] - mrow[j]);
      p1[j] = __expf(sc[1][j] - mrow[j]);
      float ps = p0[j] + p1[j];
      ps += __shfl_xor(ps, 1);
      ps += __shfl_xor(ps, 2);
      ps += __shfl_xor(ps, 4);
      ps += __shfl_xor(ps, 8);
      srow[j] = srow[j] * corr[j] + ps;
    }
#pragma unroll
    for (int n = 0; n < 5; ++n)
#pragma unroll
      for (int j = 0; j < 4; ++j)
        oacc[n][j] *= corr[j];
    // P (16x32) -> LDS transpose staging
#pragma unroll
    for (int j = 0; j < 4; ++j) {
      int row = lg * 4 + j;
      lpw[row * 32 + l15] = f2bf(p0[j]);
      lpw[row * 32 + 16 + l15] = f2bf(p1[j]);
    }
    __syncthreads();
    short8 pa = *(const short8*)&lpw[l15 * 32 + lg * 8];
    const ushort* vrow = vbase + kc * 32 + lg * 8;
#pragma unroll
    for (int n = 0; n < 5; ++n) {
      short8 vb = *(const short8*)(vrow + (size_t)(n * 16 + l15) * 4096);
      oacc[n] = mfma16(pa, vb, oacc[n]);
    }
    __syncthreads();
  }
#pragma unroll
  for (int j = 0; j < 4; ++j) {
    float inv = 1.f / srow[j];
    int row = q0 + lg * 4 + j;
#pragma unroll
    for (int n = 0; n < 5; ++n) {
      int col = n * 16 + l15;
      if (col < 72)
        attn_out[(size_t)row * 1152 + h * 72 + col] = f2bf(oacc[n][j] * inv);
    }
  }
}

// ---------------- launch
extern "C" void kernel_launch(void* const* d_in, const int* in_sizes, int n_in,
                              void* d_out, int out_size, void* d_ws, size_t ws_size,
                              hipStream_t stream) {
  (void)in_sizes; (void)n_in; (void)out_size;
  const float* hidden = (const float*)d_in[0];
  // d_in[1] = cu_seqlens: always arange(9)*512 (uniform 512 segments), handled structurally
  const float* ropec = (const float*)d_in[2];
  const float* ropes = (const float*)d_in[3];
  const float* n0s = (const float*)d_in[4];
  const float* n0b = (const float*)d_in[5];
  const float* wqkv = (const float*)d_in[6];
  const float* bqkv = (const float*)d_in[7];
  const float* wo = (const float*)d_in[8];
  const float* bo = (const float*)d_in[9];
  const float* n1s = (const float*)d_in[10];
  const float* n1b = (const float*)d_in[11];
  const float* wfc0 = (const float*)d_in[12];
  const float* bfc0 = (const float*)d_in[13];
  const float* wfc1 = (const float*)d_in[14];
  const float* bfc1 = (const float*)d_in[15];
  float* out = (float*)d_out;

  char* ws = (char*)d_ws;
  // workspace layout (bytes)
  ushort* x_bf   = (ushort*)(ws + 0);            //  9,437,184  (4096x1152 bf16)
  ushort* wqkv_t = (ushort*)(ws + 9437184);      //  7,962,624  (3456x1152 bf16)
  ushort* wo_t   = (ushort*)(ws + 17399808);     //  2,654,208  (1152x1152)
  ushort* fc0_t  = (ushort*)(ws + 20054016);     // 10,027,008  (4352x1152)
  ushort* fc1_t  = (ushort*)(ws + 30081024);     // 10,027,008  (1152x4352)
  ushort* qkv_bf = (ushort*)(ws + 40108032);     // 28,311,552  (4096x3456 bf16)
  ushort* mid    = (ushort*)(ws + 40108032);     // 35,651,584  (4096x4352 bf16) aliases qkv_bf (dead by then)
  ushort* q_pad  = (ushort*)(ws + 96731136);     // 12,582,912  (16x4096x96)
  ushort* k_pad  = (ushort*)(ws + 109314048);    // 12,582,912
  ushort* vt     = (ushort*)(ws + 121896960);    // 12,582,912  (16x96x4096)
  ushort* attn   = (ushort*)(ws + 134479872);    //  9,437,184  (4096x1152 bf16)
  float*  hbuf   = (float*)(ws + 143917056);     // 18,874,368  (4096x1152 f32)
  ushort* yln    = (ushort*)(ws + 162791424);    //  9,437,184
  if (ws_size < 172228608) return;

  // 1. weight transposes (f32 KxN -> bf16 NPxKP)
  wconv_t<<<dim3(36, 108), 256, 0, stream>>>(wqkv, wqkv_t, 1152, 3456, 3456, 1152);
  wconv_t<<<dim3(36, 36), 256, 0, stream>>>(wo, wo_t, 1152, 1152, 1152, 1152);
  wconv_t<<<dim3(36, 136), 256, 0, stream>>>(wfc0, fc0_t, 1152, 4304, 4352, 1152);
  wconv_t<<<dim3(136, 36), 256, 0, stream>>>(wfc1, fc1_t, 4304, 1152, 1152, 4352);

  // 2. LN0
  ln_bf16<<<4096, 256, 0, stream>>>(hidden, n0s, n0b, x_bf);

  // 3. QKV GEMM -> bf16 (grid 27x16 = 432 blocks)
  gemm8p<3><<<dim3(27, 16), 512, 0, stream>>>(x_bf, wqkv_t, bqkv, nullptr, nullptr, qkv_bf,
                                              3456, 1152, 3456);
  // 4. RoPE pack q,k ; 5. V transpose
  rope_pack<<<24576, 256, 0, stream>>>(qkv_bf, ropec, ropes, q_pad, k_pad);
  v_pack<<<1024, 256, 0, stream>>>(qkv_bf, vt);

  // 6. attention
  attn_kernel<<<1024, 256, 0, stream>>>(q_pad, k_pad, vt, attn);

  // 7. WO GEMM + residual -> h (grid 9x16 = 144)
  gemm8p<1><<<dim3(9, 16), 512, 0, stream>>>(attn, wo_t, bo, hidden, hbuf, nullptr,
                                             1152, 1152, 1152);
  // 8. LN1
  ln_bf16<<<4096, 256, 0, stream>>>(hbuf, n1s, n1b, yln);

  // 9. FC0 GEMM + gelu -> mid (grid 34x16 = 544)
  gemm8p<2><<<dim3(34, 16), 512, 0, stream>>>(yln, fc0_t, bfc0, nullptr, nullptr, mid,
                                              4352, 1152, 4304);
  // 10. FC1 GEMM + h residual -> out (grid 9x16 = 144)
  gemm8p<1><<<dim3(9, 16), 512, 0, stream>>>(mid, fc1_t, bfc1, hbuf, out, nullptr,
                                             1152, 4352, 1152);
}

// Round 5
// 378.271 us; speedup vs baseline: 1.1808x; 1.0094x over previous
//
#include <hip/hip_runtime.h>

// MoonVitEncoderLayer on MI355X (gfx950).
// S=4096, D=1152, H=16, HD=72 (padded to 96), MLPD=4304 (padded to 4352).
// cu_seqlens is always arange(9)*512 -> block-diagonal attention, 8 segs of 512.
// R4: cross-tile software-pipelined GEMM: 256x128xBK64, 8 waves, 3-buffer LDS
//     ring, frags(t+1) ds_read during MFMA(t), stage(t+3) in flight, one
//     barrier + counted vmcnt(6)/lgkmcnt(0) per K-tile. fc1 split-K2 + reduce.

#define DEV __device__ __forceinline__

typedef __attribute__((ext_vector_type(8))) short short8;
typedef __attribute__((ext_vector_type(4))) float f32x4;

typedef const void __attribute__((address_space(1))) gvoid;
typedef void __attribute__((address_space(3))) lvoid;

DEV ushort f2bf(float f) {
  union { float f; unsigned u; } x; x.f = f;
  unsigned r = (x.u + 0x7FFFu + ((x.u >> 16) & 1u)) >> 16;
  return (ushort)r;
}

DEV float bf2f(ushort u) {
  union { unsigned u; float f; } x; x.u = (unsigned)u << 16;
  return x.f;
}

DEV void gload_lds16(const void* g, void* l) {
  __builtin_amdgcn_global_load_lds((gvoid*)g, (lvoid*)l, 16, 0, 0);
}

DEV f32x4 mfma16(short8 a, short8 b, f32x4 c) {
  return __builtin_amdgcn_mfma_f32_16x16x32_bf16(a, b, c, 0, 0, 0);
}

DEV float gelu_tanh(float x) {
  float x3 = x * x * x;
  return 0.5f * x * (1.f + tanhf(0.7978845608f * (x + 0.044715f * x3)));
}

// ---------------- weight convert + transpose: src f32 (K,N) -> dst bf16 (NP,KP), zero-padded
__global__ void wconv_t(const float* __restrict__ src, ushort* __restrict__ dst,
                        int K, int N, int NP, int KP) {
  __shared__ float tile[32][33];
  const int k0 = blockIdx.x * 32, n0 = blockIdx.y * 32;
  const int tx = threadIdx.x & 31, ty = threadIdx.x >> 5; // ty 0..7
#pragma unroll
  for (int i = 0; i < 4; ++i) {
    int r = ty + i * 8;
    float v = 0.f;
    if (k0 + r < K && n0 + tx < N) v = src[(size_t)(k0 + r) * N + n0 + tx];
    tile[tx][r] = v;
  }
  __syncthreads();
#pragma unroll
  for (int i = 0; i < 4; ++i) {
    int r = ty + i * 8;
    dst[(size_t)(n0 + r) * KP + k0 + tx] = f2bf(tile[r][tx]);
  }
}

// ---------------- LayerNorm row kernel: f32 (4096,1152) -> bf16
__global__ __launch_bounds__(256) void ln_bf16(const float* __restrict__ x,
                                               const float* __restrict__ sc,
                                               const float* __restrict__ bi,
                                               ushort* __restrict__ out) {
  const int row = blockIdx.x, tid = threadIdx.x;
  const float* xr = x + (size_t)row * 1152;
  const int n = (tid < 128) ? 5 : 4;
  float vals[5];
  float s = 0.f, s2 = 0.f;
#pragma unroll
  for (int i = 0; i < 5; ++i) {
    if (i < n) { float v = xr[tid + i * 256]; vals[i] = v; s += v; s2 += v * v; }
  }
#pragma unroll
  for (int off = 32; off; off >>= 1) { s += __shfl_xor(s, off); s2 += __shfl_xor(s2, off); }
  __shared__ float rs[4], rs2[4];
  if ((tid & 63) == 0) { rs[tid >> 6] = s; rs2[tid >> 6] = s2; }
  __syncthreads();
  s = rs[0] + rs[1] + rs[2] + rs[3];
  s2 = rs2[0] + rs2[1] + rs2[2] + rs2[3];
  const float mean = s * (1.f / 1152.f);
  const float var = s2 * (1.f / 1152.f) - mean * mean;
  const float rstd = rsqrtf(var + 1e-5f);
  ushort* orow = out + (size_t)row * 1152;
  for (int i = 0; i < n; ++i) {
    int c = tid + i * 256;
    orow[c] = f2bf((vals[i] - mean) * rstd * sc[c] + bi[c]);
  }
}

// ---------------- GEMM: A (M,K) bf16 rm, Bt (N,K) bf16 rm, C = A*B
// Cross-tile pipelined: BM=256, BN=128, BK=64, 512 thr (8 waves 4Mx2N),
// per-wave 64x64 (acc[4][4]). 3-buffer LDS ring (144KB):
//   iter t: ds_read frags(t+1) | stage tile t+3 | 32 MFMA on frags(t) |
//           lgkmcnt(0) | vmcnt(6) (certifies tile t+2; never 0 mid-loop) | barrier
// LDS XOR-swizzle (R4-verified, conflicts==0): phys chunk = logical ^ (row&7),
// staged via pre-swizzled global source, read with cph = (ks*4+lg)^(l15&7).
// EPI 0: outf[+bz*M*N] = C            (split-K partial, no bias)
// EPI 1: outf = resid + C + bias      (wo -> h)
// EPI 2: outh = bf16(gelu(C+bias))    (fc0 -> mid)
// EPI 3: outh = bf16(C + bias)        (qkv)
template <int EPI>
__global__ __launch_bounds__(512, 2) void gemm_p(
    const ushort* __restrict__ A, const ushort* __restrict__ Bt,
    const float* __restrict__ bias, const float* __restrict__ resid,
    float* __restrict__ outf, ushort* __restrict__ outh,
    int N, int Kstride, int NT, int n_valid) {
  __shared__ ushort L[3][24576]; // per buf: A 256x64 (16384) + B 128x64 (8192)
  const int tid = threadIdx.x;
  const int lane = tid & 63, wave = tid >> 6;
  const int l15 = lane & 15, lg = lane >> 4;

  // XCD-aware bijective swizzle over the flat grid (all grids %8 == 0)
  const int nx = gridDim.x, ny = gridDim.y;
  const int nwg = nx * ny * gridDim.z;
  int flat = (blockIdx.z * ny + blockIdx.y) * nx + blockIdx.x;
  flat = (flat & 7) * (nwg >> 3) + (flat >> 3);
  const int bx = flat % nx;
  const int rem = flat / nx;
  const int by = rem % ny;
  const int bz = rem / ny;
  const int m0 = by * 256, n0 = bx * 128;
  const int k0 = bz * NT * 64; // split-K window

  // staging: A chunk c = i*512+tid -> row i*64+(tid>>3), kchunk (tid&7)^(row&7)
  const int swz = ((tid & 7) ^ ((tid >> 3) & 7)) * 8;
  const int rstg = tid >> 3;
  const ushort* Ag = A + (size_t)(m0 + rstg) * Kstride + k0 + swz;
  const ushort* Bg = Bt + (size_t)(n0 + rstg) * Kstride + k0 + swz;

  auto stage = [&](int b, int t) { // 6 gload_lds per thread
    ushort* d = &L[b][0];
#pragma unroll
    for (int i = 0; i < 4; ++i)
      gload_lds16(Ag + ((size_t)i * 64) * Kstride + t * 64,
                  d + (i * 512 + wave * 64) * 8);
#pragma unroll
    for (int i = 0; i < 2; ++i)
      gload_lds16(Bg + ((size_t)i * 64) * Kstride + t * 64,
                  d + 16384 + (i * 512 + wave * 64) * 8);
  };

  const int wm = (wave >> 1) * 64, wn = (wave & 1) * 64;
  const int cph0 = (lg ^ (l15 & 7)) * 8;
  const int cph1 = ((4 + lg) ^ (l15 & 7)) * 8;

  auto rdfrag = [&](int b, short8 (&fa)[4][2], short8 (&fb)[4][2]) {
    const ushort* la = &L[b][0];
    const ushort* lb = &L[b][16384];
#pragma unroll
    for (int mf = 0; mf < 4; ++mf) {
      fa[mf][0] = *(const short8*)&la[(wm + mf * 16 + l15) * 64 + cph0];
      fa[mf][1] = *(const short8*)&la[(wm + mf * 16 + l15) * 64 + cph1];
    }
#pragma unroll
    for (int nf = 0; nf < 4; ++nf) {
      fb[nf][0] = *(const short8*)&lb[(wn + nf * 16 + l15) * 64 + cph0];
      fb[nf][1] = *(const short8*)&lb[(wn + nf * 16 + l15) * 64 + cph1];
    }
  };

  f32x4 acc[4][4] = {};
  short8 fa[2][4][2], fb[2][4][2];

  // prologue: stage tiles 0,1,2; certify 0 AND 1 (t=0 body reads tile 1)
  stage(0, 0); stage(1, 1); stage(2, 2);
  asm volatile("s_waitcnt vmcnt(6)" ::: "memory");
  __builtin_amdgcn_s_barrier();
  rdfrag(0, fa[0], fb[0]);

  int b0 = 0, b1 = 1; // b0 = t%3, b1 = (t+1)%3

#define GBODY(TT, CUR, NXT)                                                   \
  {                                                                           \
    const int _t = (TT);                                                      \
    if (_t + 1 < NT) rdfrag(b1, fa[NXT], fb[NXT]);                            \
    if (_t + 3 < NT) stage(b0, _t + 3);                                       \
    __builtin_amdgcn_s_setprio(1);                                            \
    _Pragma("unroll") for (int mf = 0; mf < 4; ++mf)                          \
      _Pragma("unroll") for (int nf = 0; nf < 4; ++nf) {                      \
        acc[mf][nf] = mfma16(fa[CUR][mf][0], fb[CUR][nf][0], acc[mf][nf]);    \
        acc[mf][nf] = mfma16(fa[CUR][mf][1], fb[CUR][nf][1], acc[mf][nf]);    \
      }                                                                       \
    __builtin_amdgcn_s_setprio(0);                                            \
    asm volatile("s_waitcnt lgkmcnt(0)" ::: "memory");                        \
    __builtin_amdgcn_sched_barrier(0);                                        \
    if (_t + 3 < NT) { asm volatile("s_waitcnt vmcnt(6)" ::: "memory"); }     \
    else if (_t + 2 < NT) { asm volatile("s_waitcnt vmcnt(0)" ::: "memory"); }\
    if (_t + 1 < NT) __builtin_amdgcn_s_barrier();                            \
    const int _b2 = 3 - b0 - b1; b0 = b1; b1 = _b2;                           \
  }

  for (int t = 0; t < NT; t += 2) { // NT is even for all call sites
    GBODY(t, 0, 1);
    GBODY(t + 1, 1, 0);
  }
#undef GBODY

  // epilogue
  float* outp = outf;
  if constexpr (EPI == 0) outp = outf + (size_t)bz * ((size_t)4096 * N);
  const int cb = n0 + wn + l15;
  const int rb = m0 + wm + lg * 4;
#pragma unroll
  for (int j = 0; j < 4; ++j) {
    const int col = cb + j * 16;
    const float bv = (EPI != 0 && col < n_valid) ? bias[col] : 0.f;
#pragma unroll
    for (int i = 0; i < 4; ++i) {
#pragma unroll
      for (int r = 0; r < 4; ++r) {
        const int row = rb + i * 16 + r;
        const size_t idx = (size_t)row * N + col;
        const float v = acc[i][j][r] + bv;
        if constexpr (EPI == 0) outp[idx] = v;
        else if constexpr (EPI == 1) outf[idx] = resid[idx] + v;
        else if constexpr (EPI == 2) outh[idx] = f2bf(gelu_tanh(v));
        else outh[idx] = f2bf(v);
      }
    }
  }
}

// ---------------- split-K reduce: out = hb + bias(col) + p0 + p1   (f32x4)
__global__ __launch_bounds__(256) void ksum_reduce(
    const float* __restrict__ hb, const float* __restrict__ bias,
    const float* __restrict__ p0, const float* __restrict__ p1,
    float* __restrict__ out) {
  const f32x4* hb4 = (const f32x4*)hb;
  const f32x4* b4 = (const f32x4*)bias;
  const f32x4* p04 = (const f32x4*)p0;
  const f32x4* p14 = (const f32x4*)p1;
  f32x4* o4 = (f32x4*)out;
  const int total = 4096 * 288; // 4096 x 1152 / 4
  for (int i = blockIdx.x * 256 + threadIdx.x; i < total; i += gridDim.x * 256) {
    f32x4 r = hb4[i] + b4[i % 288] + p04[i] + p14[i];
    o4[i] = r;
  }
}

// ---------------- RoPE + pack q,k: qkv bf16 (S,3456) -> q_pad,k_pad bf16 (H,S,96), q pre-scaled
__global__ void rope_pack(const ushort* __restrict__ qkv,
                          const float* __restrict__ cosp, const float* __restrict__ sinp,
                          ushort* __restrict__ qp, ushort* __restrict__ kp) {
  const int t = blockIdx.x * 256 + threadIdx.x; // S*H*96 total
  const int d = t % 96;
  const int hs = t / 96;
  const int h = hs & 15;
  const int s = hs >> 4;
  const size_t dst = ((size_t)h * 4096 + s) * 96 + d;
  if (d >= 72) { qp[dst] = 0; kp[dst] = 0; return; }
  const int i = d >> 1;
  const float c = cosp[s * 36 + i], sn = sinp[s * 36 + i];
  const size_t base = (size_t)s * 3456 + h * 72;
  const float q0 = bf2f(qkv[base + (d & ~1)]), q1 = bf2f(qkv[base + (d | 1)]);
  const float k0 = bf2f(qkv[base + 1152 + (d & ~1)]), k1 = bf2f(qkv[base + 1152 + (d | 1)]);
  float qo, ko;
  if ((d & 1) == 0) { qo = q0 * c - q1 * sn; ko = k0 * c - k1 * sn; }
  else              { qo = q0 * sn + q1 * c; ko = k0 * sn + k1 * c; }
  qp[dst] = f2bf(qo * 0.1178511302f); // 72^-0.5 folded into q
  kp[dst] = f2bf(ko);
}

// ---------------- V pack + transpose: qkv bf16 -> vt bf16 (H,96,S), d>=72 zero
__global__ void v_pack(const ushort* __restrict__ qkv, ushort* __restrict__ vt) {
  __shared__ ushort lv[96][64];
  const int b = blockIdx.x;
  const int h = b >> 6;
  const int s0 = (b & 63) << 6;
  const int tid = threadIdx.x;
#pragma unroll
  for (int it = 0; it < 24; ++it) {
    int idx = tid + it * 256; // 96*64
    int d = idx % 96, sl = idx / 96;
    lv[d][sl] = (d < 72) ? qkv[(size_t)(s0 + sl) * 3456 + 2304 + h * 72 + d] : (ushort)0;
  }
  __syncthreads();
#pragma unroll
  for (int it = 0; it < 24; ++it) {
    int idx = tid + it * 256;
    int d = idx >> 6, sl = idx & 63;
    vt[((size_t)h * 96 + d) * 4096 + s0 + sl] = lv[d][sl];
  }
}

// ---------------- block-diagonal flash attention
// grid: 16 heads * 8 segs * 8 qtiles = 1024 blocks; 4 waves, 16 q-rows each
__global__ __launch_bounds__(256) void attn_kernel(
    const ushort* __restrict__ qp, const ushort* __restrict__ kp,
    const ushort* __restrict__ vt, ushort* __restrict__ attn_out) {
  __shared__ ushort lp[4][16 * 32];
  const int tid = threadIdx.x, lane = tid & 63, wave = tid >> 6;
  const int l15 = lane & 15, lg = lane >> 4;
  const int b = blockIdx.x;
  const int h = b >> 6;
  const int rem = b & 63;
  const int seg = rem >> 3, qt = rem & 7;
  const int q0 = seg * 512 + qt * 64 + wave * 16;

  short8 aq[3];
  const ushort* qrow = qp + ((size_t)h * 4096 + q0 + l15) * 96 + lg * 8;
  aq[0] = *(const short8*)(qrow);
  aq[1] = *(const short8*)(qrow + 32);
  aq[2] = *(const short8*)(qrow + 64);

  f32x4 oacc[5] = {};
  float mrow[4] = {-1e30f, -1e30f, -1e30f, -1e30f};
  float srow[4] = {0.f, 0.f, 0.f, 0.f};

  const ushort* kbase = kp + ((size_t)h * 4096 + seg * 512) * 96;
  const ushort* vbase = vt + (size_t)h * 96 * 4096 + seg * 512;
  ushort* lpw = lp[wave];

  for (int kc = 0; kc < 16; ++kc) {
    f32x4 sc[2] = {};
#pragma unroll
    for (int n = 0; n < 2; ++n) {
      const ushort* krow = kbase + (size_t)(kc * 32 + n * 16 + l15) * 96 + lg * 8;
#pragma unroll
      for (int c = 0; c < 3; ++c) {
        short8 kb = *(const short8*)(krow + c * 32);
        sc[n] = mfma16(aq[c], kb, sc[n]);
      }
    }
    float corr[4];
#pragma unroll
    for (int j = 0; j < 4; ++j) {
      float v = fmaxf(sc[0][j], sc[1][j]);
      v = fmaxf(v, __shfl_xor(v, 1));
      v = fmaxf(v, __shfl_xor(v, 2));
      v = fmaxf(v, __shfl_xor(v, 4));
      v = fmaxf(v, __shfl_xor(v, 8));
      float mn = fmaxf(mrow[j], v);
      corr[j] = __expf(mrow[j] - mn);
      mrow[j] = mn;
    }
    float p0[4], p1[4];
#pragma unroll
    for (int j = 0; j < 4; ++j) {
      p0[j] = __expf(sc[0][j] - mrow[j]);
      p1[j] = __expf(sc[1][j] - mrow[j]);
      float ps = p0[j] + p1[j];
      ps += __shfl_xor(ps, 1);
      ps += __shfl_xor(ps, 2);
      ps += __shfl_xor(ps, 4);
      ps += __shfl_xor(ps, 8);
      srow[j] = srow[j] * corr[j] + ps;
    }
#pragma unroll
    for (int n = 0; n < 5; ++n)
#pragma unroll
      for (int j = 0; j < 4; ++j)
        oacc[n][j] *= corr[j];
    // P (16x32) -> LDS transpose staging
#pragma unroll
    for (int j = 0; j < 4; ++j) {
      int row = lg * 4 + j;
      lpw[row * 32 + l15] = f2bf(p0[j]);
      lpw[row * 32 + 16 + l15] = f2bf(p1[j]);
    }
    __syncthreads();
    short8 pa = *(const short8*)&lpw[l15 * 32 + lg * 8];
    const ushort* vrow = vbase + kc * 32 + lg * 8;
#pragma unroll
    for (int n = 0; n < 5; ++n) {
      short8 vb = *(const short8*)(vrow + (size_t)(n * 16 + l15) * 4096);
      oacc[n] = mfma16(pa, vb, oacc[n]);
    }
    __syncthreads();
  }
#pragma unroll
  for (int j = 0; j < 4; ++j) {
    float inv = 1.f / srow[j];
    int row = q0 + lg * 4 + j;
#pragma unroll
    for (int n = 0; n < 5; ++n) {
      int col = n * 16 + l15;
      if (col < 72)
        attn_out[(size_t)row * 1152 + h * 72 + col] = f2bf(oacc[n][j] * inv);
    }
  }
}

// ---------------- launch
extern "C" void kernel_launch(void* const* d_in, const int* in_sizes, int n_in,
                              void* d_out, int out_size, void* d_ws, size_t ws_size,
                              hipStream_t stream) {
  (void)in_sizes; (void)n_in; (void)out_size;
  const float* hidden = (const float*)d_in[0];
  // d_in[1] = cu_seqlens: always arange(9)*512 (uniform 512 segments), handled structurally
  const float* ropec = (const float*)d_in[2];
  const float* ropes = (const float*)d_in[3];
  const float* n0s = (const float*)d_in[4];
  const float* n0b = (const float*)d_in[5];
  const float* wqkv = (const float*)d_in[6];
  const float* bqkv = (const float*)d_in[7];
  const float* wo = (const float*)d_in[8];
  const float* bo = (const float*)d_in[9];
  const float* n1s = (const float*)d_in[10];
  const float* n1b = (const float*)d_in[11];
  const float* wfc0 = (const float*)d_in[12];
  const float* bfc0 = (const float*)d_in[13];
  const float* wfc1 = (const float*)d_in[14];
  const float* bfc1 = (const float*)d_in[15];
  float* out = (float*)d_out;

  char* ws = (char*)d_ws;
  // workspace layout (bytes)
  ushort* x_bf   = (ushort*)(ws + 0);            //  9,437,184  (4096x1152 bf16)
  ushort* wqkv_t = (ushort*)(ws + 9437184);      //  7,962,624  (3456x1152 bf16)
  ushort* wo_t   = (ushort*)(ws + 17399808);     //  2,654,208  (1152x1152)
  ushort* fc0_t  = (ushort*)(ws + 20054016);     // 10,027,008  (4352x1152)
  ushort* fc1_t  = (ushort*)(ws + 30081024);     // 10,027,008  (1152x4352)
  ushort* qkv_bf = (ushort*)(ws + 40108032);     // 28,311,552  (4096x3456 bf16)
  ushort* mid    = (ushort*)(ws + 40108032);     // 35,651,584  (4096x4352 bf16) aliases qkv_bf (dead by then)
  ushort* q_pad  = (ushort*)(ws + 96731136);     // 12,582,912  (16x4096x96)
  ushort* k_pad  = (ushort*)(ws + 109314048);    // 12,582,912
  ushort* vt     = (ushort*)(ws + 121896960);    // 12,582,912  (16x96x4096)
  float*  pbuf   = (float*)(ws + 96731136);      // 37,748,736  (2x 4096x1152 f32) aliases q_pad..vt (dead after attn)
  ushort* attn   = (ushort*)(ws + 134479872);    //  9,437,184  (4096x1152 bf16)
  float*  hbuf   = (float*)(ws + 143917056);     // 18,874,368  (4096x1152 f32)
  ushort* yln    = (ushort*)(ws + 162791424);    //  9,437,184
  if (ws_size < 172228608) return;

  // 1. weight transposes (f32 KxN -> bf16 NPxKP)
  wconv_t<<<dim3(36, 108), 256, 0, stream>>>(wqkv, wqkv_t, 1152, 3456, 3456, 1152);
  wconv_t<<<dim3(36, 36), 256, 0, stream>>>(wo, wo_t, 1152, 1152, 1152, 1152);
  wconv_t<<<dim3(36, 136), 256, 0, stream>>>(wfc0, fc0_t, 1152, 4304, 4352, 1152);
  wconv_t<<<dim3(136, 36), 256, 0, stream>>>(wfc1, fc1_t, 4304, 1152, 1152, 4352);

  // 2. LN0
  ln_bf16<<<4096, 256, 0, stream>>>(hidden, n0s, n0b, x_bf);

  // 3. QKV GEMM -> bf16 (grid 27x16 = 432, NT=18)
  gemm_p<3><<<dim3(27, 16), 512, 0, stream>>>(x_bf, wqkv_t, bqkv, nullptr, nullptr, qkv_bf,
                                              3456, 1152, 18, 3456);
  // 4. RoPE pack q,k ; 5. V transpose
  rope_pack<<<24576, 256, 0, stream>>>(qkv_bf, ropec, ropes, q_pad, k_pad);
  v_pack<<<1024, 256, 0, stream>>>(qkv_bf, vt);

  // 6. attention
  attn_kernel<<<1024, 256, 0, stream>>>(q_pad, k_pad, vt, attn);

  // 7. WO GEMM + residual -> h (grid 9x16 = 144, NT=18)
  gemm_p<1><<<dim3(9, 16), 512, 0, stream>>>(attn, wo_t, bo, hidden, hbuf, nullptr,
                                             1152, 1152, 18, 1152);
  // 8. LN1
  ln_bf16<<<4096, 256, 0, stream>>>(hbuf, n1s, n1b, yln);

  // 9. FC0 GEMM + gelu -> mid (grid 34x16 = 544, NT=18)
  gemm_p<2><<<dim3(34, 16), 512, 0, stream>>>(yln, fc0_t, bfc0, nullptr, nullptr, mid,
                                              4352, 1152, 18, 4304);
  // 10. FC1 GEMM split-K2 -> partials (grid 9x16x2 = 288, NT=34 each)
  gemm_p<0><<<dim3(9, 16, 2), 512, 0, stream>>>(mid, fc1_t, nullptr, nullptr, pbuf, nullptr,
                                                1152, 4352, 34, 1152);
  // 11. reduce: out = hbuf + bias + p0 + p1
  ksum_reduce<<<2048, 256, 0, stream>>>(hbuf, bfc1, pbuf, pbuf + (size_t)4096 * 1152, out);
}